// Round 2
// baseline (298.064 us; speedup 1.0000x reference)
//
#include <hip/hip_runtime.h>

#define BB 8
#define CC 64
#define HH 112
#define WW 112
#define HWs (HH * WW)                 // 12544
#define KEYN 9
#define AOST 20                        // packed AO record: 9 attn + 10 off + 1 pad (80 B, 16B-aligned)

#define PRE_PX 128                     // pixels per precompute block
#define PRE_TILES (HWs / PRE_PX)       // 98
#define PRE_NBLK (BB * PRE_TILES)      // 784

#define SMP_PX 64
#define SMP_TILES (HWs / SMP_PX)       // 196
#define SMP_NBLK (BB * SMP_TILES)      // 1568

// ds_swizzle quad butterfly (xor lane^1, lane^2) — stays within 4-lane groups
__device__ __forceinline__ float swz1(float v) {
    return __uint_as_float(__builtin_amdgcn_ds_swizzle(__float_as_uint(v), 0x041F));
}
__device__ __forceinline__ float swz2(float v) {
    return __uint_as_float(__builtin_amdgcn_ds_swizzle(__float_as_uint(v), 0x081F));
}

// ---------------------------------------------------------------------------
// Kernel 1: all three 1x1 convs as a register-blocked GEMM.
// 128 pixels/block, 256 threads (4 waves). Lane owns 2 pixels (float2 loads).
// Wave w computes key-conv outputs [16w,16w+16) and query outputs {w,w+4,...}.
// Kf written pixel-major [pix][64] straight from registers (coalesced-enough
// 16B granules that fully cover each 64B sector). Attn softmax + offsets
// packed into AO[pix][20].
// ---------------------------------------------------------------------------
__global__ __launch_bounds__(256) void precompute_kernel(
    const float* __restrict__ query, const float* __restrict__ key,
    const float* __restrict__ w_refer, const float* __restrict__ b_refer,
    const float* __restrict__ w_attn, const float* __restrict__ b_attn,
    const float* __restrict__ w_off, const float* __restrict__ b_off,
    float* __restrict__ Kf, float* __restrict__ AO)
{
    __shared__ float L[PRE_PX * 21];   // per-pixel 19 logits, stride 21 (odd: conflict-free)

    const int t = threadIdx.x;
    const int l = t & 63;
    const int w = t >> 6;
    const int blk = blockIdx.x;
    const int b = blk / PRE_TILES;
    const int s0 = (blk - b * PRE_TILES) * PRE_PX;
    const size_t inb = (size_t)b * CC * HWs + (size_t)s0 + 2 * l;

    // ---------------- key conv: wave w -> outputs [16w, 16w+16) ----------------
    float2 acc[16];
    #pragma unroll
    for (int oi = 0; oi < 16; ++oi) {
        const float bv = b_refer[w * 16 + oi];
        acc[oi].x = bv; acc[oi].y = bv;
    }
    for (int cc = 0; cc < 4; ++cc) {
        float2 in[16];
        #pragma unroll
        for (int ci = 0; ci < 16; ++ci)
            in[ci] = *reinterpret_cast<const float2*>(key + inb + (size_t)(cc * 16 + ci) * HWs);
        #pragma unroll
        for (int oi = 0; oi < 16; ++oi) {
            const float4* wr = reinterpret_cast<const float4*>(w_refer + (w * 16 + oi) * CC + cc * 16);
            #pragma unroll
            for (int c4 = 0; c4 < 4; ++c4) {
                const float4 wv = wr[c4];
                acc[oi].x = fmaf(in[c4*4+0].x, wv.x, acc[oi].x); acc[oi].y = fmaf(in[c4*4+0].y, wv.x, acc[oi].y);
                acc[oi].x = fmaf(in[c4*4+1].x, wv.y, acc[oi].x); acc[oi].y = fmaf(in[c4*4+1].y, wv.y, acc[oi].y);
                acc[oi].x = fmaf(in[c4*4+2].x, wv.z, acc[oi].x); acc[oi].y = fmaf(in[c4*4+2].y, wv.z, acc[oi].y);
                acc[oi].x = fmaf(in[c4*4+3].x, wv.w, acc[oi].x); acc[oi].y = fmaf(in[c4*4+3].y, wv.w, acc[oi].y);
            }
        }
    }
    // store Kf pixel-major: lane's 2 pixels x this wave's 16 outputs (4 float4s each)
    #pragma unroll
    for (int j = 0; j < 2; ++j) {
        const size_t px = (size_t)b * HWs + s0 + 2 * l + j;
        float* dst = Kf + px * CC + w * 16;
        #pragma unroll
        for (int m = 0; m < 4; ++m) {
            float4 v;
            v.x = j ? acc[m*4+0].y : acc[m*4+0].x;
            v.y = j ? acc[m*4+1].y : acc[m*4+1].x;
            v.z = j ? acc[m*4+2].y : acc[m*4+2].x;
            v.w = j ? acc[m*4+3].y : acc[m*4+3].x;
            *reinterpret_cast<float4*>(dst + m * 4) = v;
        }
    }

    // ---------------- query convs: 19 outputs, wave w -> {w, w+4, ...} ----------------
    float2 qacc[5];
    #pragma unroll
    for (int qi = 0; qi < 5; ++qi) {
        const int o = w + 4 * qi;
        float bv = 0.f;
        if (o < KEYN) bv = b_attn[o];
        else if (o < 19) bv = b_off[o - KEYN];
        qacc[qi].x = bv; qacc[qi].y = bv;
    }
    for (int cc = 0; cc < 4; ++cc) {
        float2 in[16];
        #pragma unroll
        for (int ci = 0; ci < 16; ++ci)
            in[ci] = *reinterpret_cast<const float2*>(query + inb + (size_t)(cc * 16 + ci) * HWs);
        #pragma unroll
        for (int qi = 0; qi < 5; ++qi) {
            const int o = w + 4 * qi;
            if (o < 19) {
                const float* wrow = (o < KEYN) ? (w_attn + o * CC) : (w_off + (o - KEYN) * CC);
                const float4* wr = reinterpret_cast<const float4*>(wrow + cc * 16);
                #pragma unroll
                for (int c4 = 0; c4 < 4; ++c4) {
                    const float4 wv = wr[c4];
                    qacc[qi].x = fmaf(in[c4*4+0].x, wv.x, qacc[qi].x); qacc[qi].y = fmaf(in[c4*4+0].y, wv.x, qacc[qi].y);
                    qacc[qi].x = fmaf(in[c4*4+1].x, wv.y, qacc[qi].x); qacc[qi].y = fmaf(in[c4*4+1].y, wv.y, qacc[qi].y);
                    qacc[qi].x = fmaf(in[c4*4+2].x, wv.z, qacc[qi].x); qacc[qi].y = fmaf(in[c4*4+2].y, wv.z, qacc[qi].y);
                    qacc[qi].x = fmaf(in[c4*4+3].x, wv.w, qacc[qi].x); qacc[qi].y = fmaf(in[c4*4+3].y, wv.w, qacc[qi].y);
                }
            }
        }
    }
    #pragma unroll
    for (int qi = 0; qi < 5; ++qi) {
        const int o = w + 4 * qi;
        if (o < 19) {
            L[(2 * l + 0) * 21 + o] = qacc[qi].x;
            L[(2 * l + 1) * 21 + o] = qacc[qi].y;
        }
    }
    __syncthreads();

    // ---------------- softmax + packed AO store (thread t -> local pixel t) ----------------
    if (t < PRE_PX) {
        float lg[KEYN], of[10];
        #pragma unroll
        for (int k = 0; k < KEYN; ++k) lg[k] = L[t * 21 + k];
        #pragma unroll
        for (int j = 0; j < 10; ++j) of[j] = L[t * 21 + KEYN + j];
        float m = lg[0];
        #pragma unroll
        for (int k = 1; k < KEYN; ++k) m = fmaxf(m, lg[k]);
        float s = 0.f;
        float e[KEYN];
        #pragma unroll
        for (int k = 0; k < KEYN; ++k) { e[k] = expf(lg[k] - m); s += e[k]; }
        const float sinv = 1.0f / s;
        #pragma unroll
        for (int k = 0; k < KEYN; ++k) e[k] *= sinv;

        const size_t pixg = (size_t)b * HWs + s0 + t;
        float4* dst = reinterpret_cast<float4*>(AO + pixg * AOST);
        dst[0] = make_float4(e[0], e[1], e[2], e[3]);
        dst[1] = make_float4(e[4], e[5], e[6], e[7]);
        dst[2] = make_float4(e[8], of[0], of[1], of[2]);
        dst[3] = make_float4(of[3], of[4], of[5], of[6]);
        dst[4] = make_float4(of[7], of[8], of[9], 0.f);
    }
}

// ---------------------------------------------------------------------------
// Kernel 2: deformable sampling. 64 px/block, wave handles 16 px serially.
// Lane split: corner g = l&3, channel-block cb = l>>2 (channels 4cb..4cb+3).
// One float4 gather per key (9 vmem/px vs 36), per-corner bilinear weight *
// attn folded into a partial f4 accumulator; one quad butterfly per pixel.
// ---------------------------------------------------------------------------
__global__ __launch_bounds__(256) void sample_kernel(
    const float* __restrict__ Kf, const float* __restrict__ AO,
    float* __restrict__ out)
{
    __shared__ float OutT[SMP_PX * 69];   // [p][69] odd stride: conflict-free final read

    const int t = threadIdx.x;
    const int l = t & 63;
    const int w = t >> 6;
    const int blk = blockIdx.x;
    const int b = blk / SMP_TILES;
    const int s0 = (blk - b * SMP_TILES) * SMP_PX;
    const size_t kfb = (size_t)b * HWs * CC;
    const int g = l & 3;
    const int cb = l >> 2;
    const int gdy = g >> 1;
    const int gdx = g & 1;

    #pragma unroll 2
    for (int i = 0; i < 16; ++i) {
        const int p = w * 16 + i;
        const int s = s0 + p;
        const int y = s / WW;
        const int x = s - y * WW;
        const size_t pixg = (size_t)b * HWs + s;

        const float4* ao = reinterpret_cast<const float4*>(AO + pixg * AOST);
        const float4 r0 = ao[0], r1 = ao[1], r2 = ao[2], r3 = ao[3], r4 = ao[4];
        const float a[KEYN]  = {r0.x, r0.y, r0.z, r0.w, r1.x, r1.y, r1.z, r1.w, r2.x};
        const float of[10]   = {r2.y, r2.z, r2.w, r3.x, r3.y, r3.z, r3.w, r4.x, r4.y, r4.z};

        float4 acc = make_float4(0.f, 0.f, 0.f, 0.f);
        #pragma unroll
        for (int k = 0; k < KEYN; ++k) {
            const float py = of[k] + (float)y;
            const float px = of[k + 1] + (float)x;
            const float fy = floorf(py), fx = floorf(px);
            const float wy1 = py - fy, wx1 = px - fx;
            const float wy0 = 1.f - wy1, wx0 = 1.f - wx1;
            const int iy = (int)fy + gdy;
            const int ix = (int)fx + gdx;
            const int yc = min(max(iy, 0), HH - 1);
            const int xc = min(max(ix, 0), WW - 1);
            const bool valid = (iy >= 0) & (iy < HH) & (ix >= 0) & (ix < WW);
            float wk = (gdy ? wy1 : wy0) * (gdx ? wx1 : wx0);
            wk = valid ? (wk * a[k]) : 0.f;
            const float4 v = *reinterpret_cast<const float4*>(
                Kf + kfb + (size_t)(yc * WW + xc) * CC + cb * 4);
            acc.x = fmaf(v.x, wk, acc.x);
            acc.y = fmaf(v.y, wk, acc.y);
            acc.z = fmaf(v.z, wk, acc.z);
            acc.w = fmaf(v.w, wk, acc.w);
        }
        // quad butterfly: sum the 4 corner partials (lanes l^1, l^2)
        acc.x += swz1(acc.x); acc.y += swz1(acc.y); acc.z += swz1(acc.z); acc.w += swz1(acc.w);
        acc.x += swz2(acc.x); acc.y += swz2(acc.y); acc.z += swz2(acc.z); acc.w += swz2(acc.w);

        if (g == 0) {
            float* d = OutT + p * 69 + cb * 4;
            d[0] = acc.x; d[1] = acc.y; d[2] = acc.z; d[3] = acc.w;
        }
    }
    __syncthreads();

    // transpose store: out[b][c][s0+l], wave w covers channels {i*4+w}
    const size_t obase = (size_t)b * CC * HWs + s0;
    #pragma unroll
    for (int i = 0; i < 16; ++i) {
        const int c = i * 4 + w;
        out[obase + (size_t)c * HWs + l] = OutT[l * 69 + c];
    }
}

extern "C" void kernel_launch(void* const* d_in, const int* in_sizes, int n_in,
                              void* d_out, int out_size, void* d_ws, size_t ws_size,
                              hipStream_t stream)
{
    const float* query   = (const float*)d_in[0];
    const float* key     = (const float*)d_in[1];
    const float* w_refer = (const float*)d_in[2];
    const float* b_refer = (const float*)d_in[3];
    const float* w_attn  = (const float*)d_in[4];
    const float* b_attn  = (const float*)d_in[5];
    const float* w_off   = (const float*)d_in[6];
    const float* b_off   = (const float*)d_in[7];
    float* out = (float*)d_out;

    float* Kf = (float*)d_ws;                               // [B*HW][64]  25.7 MB
    float* AO = Kf + (size_t)BB * HWs * CC;                 // [B*HW][20]   8.0 MB

    hipLaunchKernelGGL(precompute_kernel, dim3(PRE_NBLK), dim3(256), 0, stream,
                       query, key, w_refer, b_refer, w_attn, b_attn, w_off, b_off,
                       Kf, AO);
    hipLaunchKernelGGL(sample_kernel, dim3(SMP_NBLK), dim3(256), 0, stream,
                       Kf, AO, out);
}

// Round 3
// 220.113 us; speedup vs baseline: 1.3541x; 1.3541x over previous
//
#include <hip/hip_runtime.h>

#define BB 8
#define CC 64
#define HH 112
#define WW 112
#define HWs (HH * WW)                 // 12544
#define KEYN 9

// ---- conv_key geometry ----
#define CK_PX 64
#define CK_TILES (HWs / CK_PX)        // 196
#define CK_NBLK (BB * CK_TILES)       // 1568

// ---- fused sampler geometry ----
#define SM_PX 32
#define SM_TILES (HWs / SM_PX)        // 392
#define SM_NBLK (BB * SM_TILES)       // 3136

// LDS float offsets for the fused kernel
#define OFF_QIN  0                    // Qin[64][32]  (2048) -> reused as OutT[32][69] (2208)
#define OFF_WQ   2208                 // Wq[64][20]   (1280) -> reused as AOs[32][20] (640)
#define OFF_SB   3488                 // Sb[20] biases
#define OFF_L    3508                 // L[32][21]    (672)
#define SM_LDS   4180                 // total floats (16.7 KB)

__device__ __forceinline__ float swz1(float v) {
    return __uint_as_float(__builtin_amdgcn_ds_swizzle(__float_as_uint(v), 0x041F));
}
__device__ __forceinline__ float swz2(float v) {
    return __uint_as_float(__builtin_amdgcn_ds_swizzle(__float_as_uint(v), 0x081F));
}

// ---------------------------------------------------------------------------
// conv_key: Kf[b*HW+px][64] = W_refer @ key + b_refer   (pixel-major output)
// Block: 256 thr, 64-px tile. LDS-staged input [k][px] + transposed weights
// [k][o]. Thread = (px4 = t&15, o4 = t>>4): 4px x 4out register tile.
// ---------------------------------------------------------------------------
__global__ __launch_bounds__(256, 4) void conv_key_kernel(
    const float* __restrict__ key, const float* __restrict__ w_refer,
    const float* __restrict__ b_refer, float* __restrict__ Kf)
{
    __shared__ float Xin[64 * 64];   // [k][px]
    __shared__ float Wt[64 * 64];    // [k][o]

    const int t = threadIdx.x;
    const int blk = blockIdx.x;
    const int b = blk / CK_TILES;
    const int s0 = (blk - b * CK_TILES) * CK_PX;
    const size_t inb = (size_t)b * CC * HWs + s0;

    // stage transposed weights: 1024 float4 reads, scatter to [k][o]
    #pragma unroll
    for (int m = 0; m < 4; ++m) {
        const int f = t + 256 * m;            // [0,1024)
        const int o = f >> 4;
        const int q = f & 15;
        const float4 wv = *reinterpret_cast<const float4*>(w_refer + o * CC + q * 4);
        Wt[(q * 4 + 0) * 64 + o] = wv.x;
        Wt[(q * 4 + 1) * 64 + o] = wv.y;
        Wt[(q * 4 + 2) * 64 + o] = wv.z;
        Wt[(q * 4 + 3) * 64 + o] = wv.w;
    }
    // stage input tile: 1024 float4, coalesced per k-row
    #pragma unroll
    for (int m = 0; m < 4; ++m) {
        const int f = t + 256 * m;
        const int k = f >> 4;
        const int p4 = f & 15;
        *reinterpret_cast<float4*>(&Xin[k * 64 + p4 * 4]) =
            *reinterpret_cast<const float4*>(key + inb + (size_t)k * HWs + p4 * 4);
    }
    __syncthreads();

    const int px4 = t & 15;
    const int o4 = t >> 4;
    const float4 bias = *reinterpret_cast<const float4*>(b_refer + 4 * o4);
    float4 acc[4];
    #pragma unroll
    for (int pi = 0; pi < 4; ++pi) acc[pi] = bias;

    #pragma unroll 8
    for (int k = 0; k < 64; ++k) {
        const float4 a  = *reinterpret_cast<const float4*>(&Xin[k * 64 + 4 * px4]);
        const float4 wv = *reinterpret_cast<const float4*>(&Wt[k * 64 + 4 * o4]);
        const float ap[4] = {a.x, a.y, a.z, a.w};
        #pragma unroll
        for (int pi = 0; pi < 4; ++pi) {
            acc[pi].x = fmaf(ap[pi], wv.x, acc[pi].x);
            acc[pi].y = fmaf(ap[pi], wv.y, acc[pi].y);
            acc[pi].z = fmaf(ap[pi], wv.z, acc[pi].z);
            acc[pi].w = fmaf(ap[pi], wv.w, acc[pi].w);
        }
    }

    const size_t ob = ((size_t)b * HWs + s0 + 4 * px4) * CC + 4 * o4;
    #pragma unroll
    for (int pi = 0; pi < 4; ++pi)
        *reinterpret_cast<float4*>(Kf + ob + (size_t)pi * CC) = acc[pi];
}

// ---------------------------------------------------------------------------
// Fused: query conv (20 outs) -> softmax -> deformable sampling -> out.
// Block: 256 thr, 32-px tile. batch = blockIdx&7 (batch<->XCD L2 locality).
// Sampling: lane = (corner g = l&3, ch-quad cb = l>>2); 9 float4 gathers/px;
// quad ds_swizzle reduction; output transposed through LDS.
// ---------------------------------------------------------------------------
__global__ __launch_bounds__(256, 6) void fused_sample_kernel(
    const float* __restrict__ query, const float* __restrict__ w_attn,
    const float* __restrict__ b_attn, const float* __restrict__ w_off,
    const float* __restrict__ b_off, const float* __restrict__ Kf,
    float* __restrict__ out)
{
    __shared__ float S[SM_LDS];
    float* Qin = S + OFF_QIN;     // [64][32]
    float* Wq  = S + OFF_WQ;      // [64][20]
    float* Sb  = S + OFF_SB;      // [20]
    float* L   = S + OFF_L;       // [32][21]
    float* AOs = S + OFF_WQ;      // [32][20]  (overlays Wq after conv)
    float* OutT = S + OFF_QIN;    // [32][69]  (overlays Qin after conv)

    const int t = threadIdx.x;
    const int l = t & 63;
    const int w = t >> 6;
    const int blk = blockIdx.x;
    const int b = blk & 7;                      // batch == XCD (round-robin dispatch)
    const int tile = blk >> 3;
    const int s0 = tile * SM_PX;
    const size_t qb = (size_t)b * CC * HWs + s0;
    const size_t kfb = (size_t)b * HWs * CC;

    // ---- stage query tile [k][px]: 512 float4
    #pragma unroll
    for (int m = 0; m < 2; ++m) {
        const int f = t + 256 * m;
        const int k = f >> 3;
        const int p4 = f & 7;
        *reinterpret_cast<float4*>(&Qin[k * 32 + 4 * p4]) =
            *reinterpret_cast<const float4*>(query + qb + (size_t)k * HWs + 4 * p4);
    }
    // ---- stage transposed query weights [k][20] (19 real cols + zero col)
    for (int f = t; f < 304; f += 256) {
        const int r = f >> 4;      // output row 0..18
        const int q = f & 15;
        const float* src = (r < KEYN) ? (w_attn + r * CC) : (w_off + (r - KEYN) * CC);
        const float4 wv = *reinterpret_cast<const float4*>(src + q * 4);
        Wq[(q * 4 + 0) * 20 + r] = wv.x;
        Wq[(q * 4 + 1) * 20 + r] = wv.y;
        Wq[(q * 4 + 2) * 20 + r] = wv.z;
        Wq[(q * 4 + 3) * 20 + r] = wv.w;
    }
    if (t < 64) Wq[t * 20 + 19] = 0.f;          // zero pad column
    if (t < 20) Sb[t] = (t < KEYN) ? b_attn[t] : (t < 19 ? b_off[t - KEYN] : 0.f);
    __syncthreads();

    // ---- query conv: thread = (px = t&31, og = t>>5), og<5 -> outs 4og..4og+3
    {
        const int px = t & 31;
        const int og = t >> 5;
        if (og < 5) {
            const int o4 = 4 * og;
            float4 acc = *reinterpret_cast<const float4*>(&Sb[o4]);
            #pragma unroll 8
            for (int k = 0; k < 64; ++k) {
                const float a = Qin[k * 32 + px];
                const float4 wv = *reinterpret_cast<const float4*>(&Wq[k * 20 + o4]);
                acc.x = fmaf(a, wv.x, acc.x);
                acc.y = fmaf(a, wv.y, acc.y);
                acc.z = fmaf(a, wv.z, acc.z);
                acc.w = fmaf(a, wv.w, acc.w);
            }
            L[px * 21 + o4 + 0] = acc.x;
            L[px * 21 + o4 + 1] = acc.y;
            L[px * 21 + o4 + 2] = acc.z;
            L[px * 21 + o4 + 3] = acc.w;
        }
    }
    __syncthreads();

    // ---- softmax + pack AO (overlays Wq; Wq is dead now)
    if (t < SM_PX) {
        float lg[KEYN], of[10];
        #pragma unroll
        for (int k = 0; k < KEYN; ++k) lg[k] = L[t * 21 + k];
        #pragma unroll
        for (int j = 0; j < 10; ++j) of[j] = L[t * 21 + KEYN + j];
        float m = lg[0];
        #pragma unroll
        for (int k = 1; k < KEYN; ++k) m = fmaxf(m, lg[k]);
        float s = 0.f, e[KEYN];
        #pragma unroll
        for (int k = 0; k < KEYN; ++k) { e[k] = expf(lg[k] - m); s += e[k]; }
        const float sinv = 1.0f / s;
        float* d = AOs + t * 20;
        #pragma unroll
        for (int k = 0; k < KEYN; ++k) d[k] = e[k] * sinv;
        #pragma unroll
        for (int j = 0; j < 10; ++j) d[KEYN + j] = of[j];
        d[19] = 0.f;
    }
    __syncthreads();

    // ---- sampling: wave w -> px [8w, 8w+8)
    const int g = l & 3;
    const int cb = l >> 2;
    const int gdy = g >> 1;
    const int gdx = g & 1;
    const int y0 = s0 / WW;
    const int x0r = s0 - y0 * WW;

    #pragma unroll 2
    for (int i = 0; i < 8; ++i) {
        const int p = w * 8 + i;
        int x = x0r + p;
        int y = y0;
        if (x >= WW) { x -= WW; y += 1; }

        const float4* ao = reinterpret_cast<const float4*>(AOs + p * 20);
        const float4 r0 = ao[0], r1 = ao[1], r2 = ao[2], r3 = ao[3], r4 = ao[4];
        const float a[KEYN] = {r0.x, r0.y, r0.z, r0.w, r1.x, r1.y, r1.z, r1.w, r2.x};
        const float of[10]  = {r2.y, r2.z, r2.w, r3.x, r3.y, r3.z, r3.w, r4.x, r4.y, r4.z};

        float4 acc = make_float4(0.f, 0.f, 0.f, 0.f);
        #pragma unroll
        for (int k = 0; k < KEYN; ++k) {
            const float py = of[k] + (float)y;
            const float px = of[k + 1] + (float)x;
            const float fy = floorf(py), fx = floorf(px);
            const float wy1 = py - fy, wx1 = px - fx;
            const float wy0 = 1.f - wy1, wx0 = 1.f - wx1;
            const int iy = (int)fy + gdy;
            const int ix = (int)fx + gdx;
            const int yc = min(max(iy, 0), HH - 1);
            const int xc = min(max(ix, 0), WW - 1);
            const bool valid = (iy >= 0) & (iy < HH) & (ix >= 0) & (ix < WW);
            float wk = (gdy ? wy1 : wy0) * (gdx ? wx1 : wx0);
            wk = valid ? (wk * a[k]) : 0.f;
            const float4 v = *reinterpret_cast<const float4*>(
                Kf + kfb + (size_t)(yc * WW + xc) * CC + cb * 4);
            acc.x = fmaf(v.x, wk, acc.x);
            acc.y = fmaf(v.y, wk, acc.y);
            acc.z = fmaf(v.z, wk, acc.z);
            acc.w = fmaf(v.w, wk, acc.w);
        }
        acc.x += swz1(acc.x); acc.y += swz1(acc.y); acc.z += swz1(acc.z); acc.w += swz1(acc.w);
        acc.x += swz2(acc.x); acc.y += swz2(acc.y); acc.z += swz2(acc.z); acc.w += swz2(acc.w);

        if (g == 0) {
            float* d = OutT + p * 69 + cb * 4;   // Qin is dead; overlay OK
            d[0] = acc.x; d[1] = acc.y; d[2] = acc.z; d[3] = acc.w;
        }
    }
    __syncthreads();

    // ---- transposed store: out[b][c][s0+px]
    const size_t ob = (size_t)b * CC * HWs + s0;
    #pragma unroll
    for (int m = 0; m < 8; ++m) {
        const int f = t + 256 * m;
        const int c = f >> 5;
        const int px = f & 31;
        out[ob + (size_t)c * HWs + px] = OutT[px * 69 + c];
    }
}

extern "C" void kernel_launch(void* const* d_in, const int* in_sizes, int n_in,
                              void* d_out, int out_size, void* d_ws, size_t ws_size,
                              hipStream_t stream)
{
    const float* query   = (const float*)d_in[0];
    const float* key     = (const float*)d_in[1];
    const float* w_refer = (const float*)d_in[2];
    const float* b_refer = (const float*)d_in[3];
    const float* w_attn  = (const float*)d_in[4];
    const float* b_attn  = (const float*)d_in[5];
    const float* w_off   = (const float*)d_in[6];
    const float* b_off   = (const float*)d_in[7];
    float* out = (float*)d_out;

    float* Kf = (float*)d_ws;   // [B*HW][64] pixel-major, 25.7 MB

    hipLaunchKernelGGL(conv_key_kernel, dim3(CK_NBLK), dim3(256), 0, stream,
                       key, w_refer, b_refer, Kf);
    hipLaunchKernelGGL(fused_sample_kernel, dim3(SM_NBLK), dim3(256), 0, stream,
                       query, w_attn, b_attn, w_off, b_off, Kf, out);
}

// Round 4
// 219.380 us; speedup vs baseline: 1.3587x; 1.0033x over previous
//
#include <hip/hip_runtime.h>

#define BB 8
#define CC 64
#define HH 112
#define WW 112
#define HWs (HH * WW)                 // 12544
#define KEYN 9

// ---- conv_key geometry ----
#define CK_PX 128
#define CK_TILES (HWs / CK_PX)        // 98
#define CK_NBLK (BB * CK_TILES)       // 784
#define WTS 68                        // Wt row stride (floats): 68*4=272 B, 16B-aligned rows

// ---- fused sampler geometry ----
#define SM_PX 32
#define SM_TILES (HWs / SM_PX)        // 392
#define SM_NBLK (BB * SM_TILES)       // 3136

// fused-kernel LDS float offsets
#define OFF_QIN  0                    // Qin[64][32] (2048); overlaid by OutT[32][69] (2208)
#define OFF_WQ   2208                 // Wq[64][20] (1280)
#define OFF_SB   3488                 // Sb[20]
#define OFF_L    3508                 // L[32][21] (672)
#define OFF_T    4180                 // T[32][9][4] uint2 (2304 floats); even -> 8B aligned
#define SM_LDS   6484                 // 25.9 KB -> 6 blocks/CU

__device__ __forceinline__ float swz1(float v) {
    return __uint_as_float(__builtin_amdgcn_ds_swizzle(__float_as_uint(v), 0x041F));
}
__device__ __forceinline__ float swz2(float v) {
    return __uint_as_float(__builtin_amdgcn_ds_swizzle(__float_as_uint(v), 0x081F));
}

// ---------------------------------------------------------------------------
// conv_key: Kf[b*HW+px][64] = W_refer @ key + b_refer  (pixel-major output)
// 256 thr, 128px x 64out tile. thread = (og = t&7 -> outs 8og..8og+7,
// p4 = t>>3 -> px 4p4..4p4+3). Per k: 1 b128 (4 px) + 2 b128 (8 wts, 2-addr
// broadcast) -> 32 FMA. LDS 49 KB -> 3 blocks/CU.
// ---------------------------------------------------------------------------
__global__ __launch_bounds__(256, 3) void conv_key_kernel(
    const float* __restrict__ key, const float* __restrict__ w_refer,
    const float* __restrict__ b_refer, float* __restrict__ Kf)
{
    __shared__ float Xin[64 * CK_PX];   // [k][px]  32 KB
    __shared__ float Wt[64 * WTS];      // [k][o]   17.4 KB, stride 68

    const int t = threadIdx.x;
    const int blk = blockIdx.x;
    const int b = blk / CK_TILES;
    const int s0 = (blk - b * CK_TILES) * CK_PX;
    const size_t inb = (size_t)b * CC * HWs + s0;

    // stage transposed weights [k][o]: one-time scatter (bank conflicts ok)
    #pragma unroll
    for (int m = 0; m < 4; ++m) {
        const int f = t + 256 * m;            // [0,1024)
        const int o = f >> 4;
        const int q = f & 15;
        const float4 wv = *reinterpret_cast<const float4*>(w_refer + o * CC + 4 * q);
        Wt[(4 * q + 0) * WTS + o] = wv.x;
        Wt[(4 * q + 1) * WTS + o] = wv.y;
        Wt[(4 * q + 2) * WTS + o] = wv.z;
        Wt[(4 * q + 3) * WTS + o] = wv.w;
    }
    // stage input tile [k][px]: 2048 float4, coalesced
    #pragma unroll
    for (int m = 0; m < 8; ++m) {
        const int f = t + 256 * m;            // [0,2048)
        const int k = f >> 5;
        const int p8 = f & 31;
        *reinterpret_cast<float4*>(&Xin[k * CK_PX + 4 * p8]) =
            *reinterpret_cast<const float4*>(key + inb + (size_t)k * HWs + 4 * p8);
    }
    __syncthreads();

    const int og = t & 7;
    const int p4 = t >> 3;
    const float4 bias0 = *reinterpret_cast<const float4*>(b_refer + 8 * og);
    const float4 bias1 = *reinterpret_cast<const float4*>(b_refer + 8 * og + 4);
    float4 acc[4][2];
    #pragma unroll
    for (int pi = 0; pi < 4; ++pi) { acc[pi][0] = bias0; acc[pi][1] = bias1; }

    #pragma unroll 4
    for (int k = 0; k < 64; ++k) {
        const float4 a4 = *reinterpret_cast<const float4*>(&Xin[k * CK_PX + 4 * p4]);
        const float4 w0 = *reinterpret_cast<const float4*>(&Wt[k * WTS + 8 * og]);
        const float4 w1 = *reinterpret_cast<const float4*>(&Wt[k * WTS + 8 * og + 4]);
        const float ap[4] = {a4.x, a4.y, a4.z, a4.w};
        #pragma unroll
        for (int pi = 0; pi < 4; ++pi) {
            acc[pi][0].x = fmaf(ap[pi], w0.x, acc[pi][0].x);
            acc[pi][0].y = fmaf(ap[pi], w0.y, acc[pi][0].y);
            acc[pi][0].z = fmaf(ap[pi], w0.z, acc[pi][0].z);
            acc[pi][0].w = fmaf(ap[pi], w0.w, acc[pi][0].w);
            acc[pi][1].x = fmaf(ap[pi], w1.x, acc[pi][1].x);
            acc[pi][1].y = fmaf(ap[pi], w1.y, acc[pi][1].y);
            acc[pi][1].z = fmaf(ap[pi], w1.z, acc[pi][1].z);
            acc[pi][1].w = fmaf(ap[pi], w1.w, acc[pi][1].w);
        }
    }

    // store pixel-major: per instr, og-lanes tile each px row contiguously
    #pragma unroll
    for (int pi = 0; pi < 4; ++pi) {
        const size_t ob = ((size_t)b * HWs + s0 + 4 * p4 + pi) * CC + 8 * og;
        *reinterpret_cast<float4*>(Kf + ob)     = acc[pi][0];
        *reinterpret_cast<float4*>(Kf + ob + 4) = acc[pi][1];
    }
}

// ---------------------------------------------------------------------------
// Fused: query conv (19 outs) -> softmax -> (addr,weight) table -> sampling.
// 256 thr, 32-px tile, batch = blockIdx&7 (batch<->XCD L2 locality).
// Table stage computes each (px,key,corner) byte-address + folded weight ONCE
// (1152 items); sampling loop is ds_read_b64 + add + dwordx4 gather + 4 FMA.
// ---------------------------------------------------------------------------
__global__ __launch_bounds__(256, 4) void fused_sample_kernel(
    const float* __restrict__ query, const float* __restrict__ w_attn,
    const float* __restrict__ b_attn, const float* __restrict__ w_off,
    const float* __restrict__ b_off, const float* __restrict__ Kf,
    float* __restrict__ out)
{
    __shared__ float S[SM_LDS];
    float* Qin  = S + OFF_QIN;    // [64][32]
    float* Wq   = S + OFF_WQ;     // [64][20]
    float* Sb   = S + OFF_SB;     // [20]
    float* L    = S + OFF_L;      // [32][21]
    uint2* Tq   = reinterpret_cast<uint2*>(S + OFF_T);   // [32*9*4]
    float* OutT = S + OFF_QIN;    // [32][69] overlays Qin (dead after conv)

    const int t = threadIdx.x;
    const int l = t & 63;
    const int w = t >> 6;
    const int blk = blockIdx.x;
    const int b = blk & 7;                       // batch == XCD round-robin
    const int tile = blk >> 3;
    const int s0 = tile * SM_PX;
    const size_t qb = (size_t)b * CC * HWs + s0;
    const char* Kfb = reinterpret_cast<const char*>(Kf) + (size_t)b * HWs * CC * 4;

    // ---- stage query tile [k][px]
    #pragma unroll
    for (int m = 0; m < 2; ++m) {
        const int f = t + 256 * m;
        const int k = f >> 3;
        const int p4 = f & 7;
        *reinterpret_cast<float4*>(&Qin[k * 32 + 4 * p4]) =
            *reinterpret_cast<const float4*>(query + qb + (size_t)k * HWs + 4 * p4);
    }
    // ---- stage transposed query weights [k][20] + biases
    for (int f = t; f < 304; f += 256) {
        const int r = f >> 4;
        const int q = f & 15;
        const float* src = (r < KEYN) ? (w_attn + r * CC) : (w_off + (r - KEYN) * CC);
        const float4 wv = *reinterpret_cast<const float4*>(src + 4 * q);
        Wq[(4 * q + 0) * 20 + r] = wv.x;
        Wq[(4 * q + 1) * 20 + r] = wv.y;
        Wq[(4 * q + 2) * 20 + r] = wv.z;
        Wq[(4 * q + 3) * 20 + r] = wv.w;
    }
    if (t < 64) Wq[t * 20 + 19] = 0.f;
    if (t < 20) Sb[t] = (t < KEYN) ? b_attn[t] : (t < 19 ? b_off[t - KEYN] : 0.f);
    __syncthreads();

    // ---- query conv: thread = (px = t&31, og = t>>5 < 5)
    {
        const int px = t & 31;
        const int og = t >> 5;
        if (og < 5) {
            const int o4 = 4 * og;
            float4 acc = *reinterpret_cast<const float4*>(&Sb[o4]);
            #pragma unroll 8
            for (int k = 0; k < 64; ++k) {
                const float a = Qin[k * 32 + px];
                const float4 wv = *reinterpret_cast<const float4*>(&Wq[k * 20 + o4]);
                acc.x = fmaf(a, wv.x, acc.x);
                acc.y = fmaf(a, wv.y, acc.y);
                acc.z = fmaf(a, wv.z, acc.z);
                acc.w = fmaf(a, wv.w, acc.w);
            }
            L[px * 21 + o4 + 0] = acc.x;
            L[px * 21 + o4 + 1] = acc.y;
            L[px * 21 + o4 + 2] = acc.z;
            L[px * 21 + o4 + 3] = acc.w;
        }
    }
    __syncthreads();

    // ---- softmax in place: L[p][0..8] <- normalized attn
    if (t < SM_PX) {
        float lg[KEYN];
        #pragma unroll
        for (int k = 0; k < KEYN; ++k) lg[k] = L[t * 21 + k];
        float m = lg[0];
        #pragma unroll
        for (int k = 1; k < KEYN; ++k) m = fmaxf(m, lg[k]);
        float s = 0.f, e[KEYN];
        #pragma unroll
        for (int k = 0; k < KEYN; ++k) { e[k] = expf(lg[k] - m); s += e[k]; }
        const float sinv = 1.0f / s;
        #pragma unroll
        for (int k = 0; k < KEYN; ++k) L[t * 21 + k] = e[k] * sinv;
    }
    __syncthreads();

    // ---- table: (byte addr, wk = corner-weight * attn) per (px,key,corner)
    for (int f = t; f < SM_PX * KEYN * 4; f += 256) {
        const int p = f / 36;
        const int r = f - p * 36;
        const int k = r >> 2;
        const int g = r & 3;
        const int s = s0 + p;
        const int y = s / WW;
        const int x = s - y * WW;
        const float a  = L[p * 21 + k];
        const float dy = L[p * 21 + KEYN + k];
        const float dx = L[p * 21 + KEYN + k + 1];
        const float py = dy + (float)y;
        const float px = dx + (float)x;
        const float fy = floorf(py), fx = floorf(px);
        const int gdy = g >> 1, gdx = g & 1;
        const int iy = (int)fy + gdy;
        const int ix = (int)fx + gdx;
        const int yc = min(max(iy, 0), HH - 1);
        const int xc = min(max(ix, 0), WW - 1);
        const bool valid = (iy >= 0) & (iy < HH) & (ix >= 0) & (ix < WW);
        const float wy = gdy ? (py - fy) : (1.f - (py - fy));
        const float wx = gdx ? (px - fx) : (1.f - (px - fx));
        float wk = wy * wx * a;
        wk = valid ? wk : 0.f;
        const unsigned addr = (unsigned)((yc * WW + xc) * CC * 4);
        Tq[f] = make_uint2(addr, __float_as_uint(wk));
    }
    __syncthreads();

    // ---- sampling: wave w -> px [8w,8w+8); lane = (corner g, ch-quad cb)
    const int g = l & 3;
    const int cb16 = (l >> 2) * 16;

    for (int i = 0; i < 8; ++i) {
        const int p = w * 8 + i;
        const uint2* Tp = Tq + p * 36 + g;      // +k*4 becomes immediate offset

        float4 acc0 = make_float4(0.f, 0.f, 0.f, 0.f);
        float4 acc1 = make_float4(0.f, 0.f, 0.f, 0.f);
        #pragma unroll
        for (int k = 0; k < KEYN; ++k) {
            const uint2 e = Tp[k * 4];
            const float wk = __uint_as_float(e.y);
            const float4 v = *reinterpret_cast<const float4*>(Kfb + (e.x + cb16));
            if (k & 1) {
                acc1.x = fmaf(v.x, wk, acc1.x); acc1.y = fmaf(v.y, wk, acc1.y);
                acc1.z = fmaf(v.z, wk, acc1.z); acc1.w = fmaf(v.w, wk, acc1.w);
            } else {
                acc0.x = fmaf(v.x, wk, acc0.x); acc0.y = fmaf(v.y, wk, acc0.y);
                acc0.z = fmaf(v.z, wk, acc0.z); acc0.w = fmaf(v.w, wk, acc0.w);
            }
        }
        float4 acc;
        acc.x = acc0.x + acc1.x; acc.y = acc0.y + acc1.y;
        acc.z = acc0.z + acc1.z; acc.w = acc0.w + acc1.w;

        acc.x += swz1(acc.x); acc.y += swz1(acc.y); acc.z += swz1(acc.z); acc.w += swz1(acc.w);
        acc.x += swz2(acc.x); acc.y += swz2(acc.y); acc.z += swz2(acc.z); acc.w += swz2(acc.w);

        if (g == 0) {
            float* d = OutT + p * 69 + (cb16 >> 2);
            d[0] = acc.x; d[1] = acc.y; d[2] = acc.z; d[3] = acc.w;
        }
    }
    __syncthreads();

    // ---- transposed store: out[b][c][s0+px]
    const size_t ob = (size_t)b * CC * HWs + s0;
    #pragma unroll
    for (int m = 0; m < 8; ++m) {
        const int f = t + 256 * m;
        const int c = f >> 5;
        const int px = f & 31;
        out[ob + (size_t)c * HWs + px] = OutT[px * 69 + c];
    }
}

extern "C" void kernel_launch(void* const* d_in, const int* in_sizes, int n_in,
                              void* d_out, int out_size, void* d_ws, size_t ws_size,
                              hipStream_t stream)
{
    const float* query   = (const float*)d_in[0];
    const float* key     = (const float*)d_in[1];
    const float* w_refer = (const float*)d_in[2];
    const float* b_refer = (const float*)d_in[3];
    const float* w_attn  = (const float*)d_in[4];
    const float* b_attn  = (const float*)d_in[5];
    const float* w_off   = (const float*)d_in[6];
    const float* b_off   = (const float*)d_in[7];
    float* out = (float*)d_out;

    float* Kf = (float*)d_ws;   // [B*HW][64] pixel-major, 25.7 MB

    hipLaunchKernelGGL(conv_key_kernel, dim3(CK_NBLK), dim3(256), 0, stream,
                       key, w_refer, b_refer, Kf);
    hipLaunchKernelGGL(fused_sample_kernel, dim3(SM_NBLK), dim3(256), 0, stream,
                       query, w_attn, b_attn, w_off, b_off, Kf, out);
}